// Round 18
// baseline (185.341 us; speedup 1.0000x reference)
//
#include <hip/hip_runtime.h>
#include <hip/hip_bf16.h>
#include <cstdint>

#define N_DIM 4096
#define K_DIM 2048           // i8 elements per row
#define NKT 32               // 32 K-tiles of 64
#define QSCALE 24.0f
#define QINV (1.0f / 24.0f)
#define FIXP 67108864.0f     // 2^26 fixed-point scale for deterministic sum

typedef float floatx4 __attribute__((ext_vector_type(4)));
typedef int intx4 __attribute__((ext_vector_type(4)));
typedef unsigned short ushort8 __attribute__((ext_vector_type(8)));
typedef unsigned long long ull;

__device__ __forceinline__ unsigned short f2bf(float f) {
    unsigned int u = __builtin_bit_cast(unsigned int, f);
    unsigned int r = (u + 0x7fffu + ((u >> 16) & 1u)) >> 16;  // RNE
    return (unsigned short)r;
}

__device__ __forceinline__ float bf2f(unsigned short b) {
    return __uint_as_float(((unsigned)b) << 16);
}

__device__ __forceinline__ void gld_lds16(const void* g, void* l) {
    __builtin_amdgcn_global_load_lds(
        (const __attribute__((address_space(1))) unsigned int*)g,
        (__attribute__((address_space(3))) unsigned int*)l,
        16, 0, 0);
}

// ---- Kernel 0: quantize fp32 -> int8 (scale 24) into k-major panels --------
// Qt layout: byte(kslot, row) = (kslot*4096 + row)*16, kslot = k/16 (0..127).
// Blocks 0..15 additionally convert tgt (int32, labels 0..63) -> tgt8 (int8).
__global__ __launch_bounds__(256)
void prep_kernel(const float* __restrict__ X, const int* __restrict__ tgt,
                 char* __restrict__ Qt, int* __restrict__ sqi,
                 char* __restrict__ tgt8) {
    const int row = blockIdx.x;
    const int tid = threadIdx.x;
    if (row < 16) tgt8[row * 256 + tid] = (char)tgt[row * 256 + tid];
    const float* xr = X + (size_t)row * K_DIM;
    floatx4 a = *(const floatx4*)(xr + tid * 8);
    floatx4 b = *(const floatx4*)(xr + tid * 8 + 4);
    int s = 0;
    unsigned lo = 0, hi = 0;
#pragma unroll
    for (int e = 0; e < 4; ++e) {
        int v = __float2int_rn(a[e] * QSCALE);
        v = min(127, max(-127, v));
        s += v * v;
        lo |= ((unsigned)(v & 0xff)) << (8 * e);
        int w = __float2int_rn(b[e] * QSCALE);
        w = min(127, max(-127, w));
        s += w * w;
        hi |= ((unsigned)(w & 0xff)) << (8 * e);
    }
    *(int2*)(Qt + ((size_t)(tid >> 1) * 4096 + row) * 16 + (tid & 1) * 8) =
        make_int2((int)lo, (int)hi);
#pragma unroll
    for (int off = 32; off; off >>= 1) s += __shfl_down(s, off);
    __shared__ int wsum[4];
    const int wave = tid >> 6, lane = tid & 63;
    if (lane == 0) wsum[wave] = s;
    __syncthreads();
    if (tid == 0) sqi[row] = wsum[0] + wsum[1] + wsum[2] + wsum[3];
}

// ---- Kernel 1: 256x256 int8 MFMA GEMM + bf16 distance epilogue -------------
// R17 kernel verbatim (best measured: 45.0 us, VGPR 108, 0 bank conflicts,
// FETCH 33 MB, absmax 0.0625). Merged single phase per K-tile, quad-buffered
// 128KB LDS:
//   tile t: [RD 12 b128 | STG all 4 halves of (t+2) | vmcnt(4) | BAR | 32 MFMA]
#define BAR() __builtin_amdgcn_s_barrier()
#define PRIO1() __builtin_amdgcn_s_setprio(1)
#define PRIO0() __builtin_amdgcn_s_setprio(0)
#define VMCNT4() asm volatile("s_waitcnt vmcnt(4)" ::: "memory")
#define VMCNT0() asm volatile("s_waitcnt vmcnt(0)" ::: "memory")
#define MM8(MHI, AF) { _Pragma("unroll") for (int n_ = 0; n_ < 4; ++n_) { \
    _Pragma("unroll") for (int m_ = 0; m_ < 4; ++m_) { \
        acc[MHI][n_][m_] = __builtin_amdgcn_mfma_i32_16x16x64_i8( \
            AF[m_], bfv[n_], acc[MHI][n_][m_], 0, 0, 0); } } }
#define KTB 262144   // one K-tile advance in Qt = 4 kslots * 4096 rows * 16B
#define STG_ALL(KT, BB) { \
    gld_lds16(bSt + (size_t)(KT) * KTB,        lds + (BB) + 16384 + widB); \
    gld_lds16(bSt + (size_t)(KT) * KTB + 2048, lds + (BB) + 24576 + widB); \
    gld_lds16(aSt + (size_t)(KT) * KTB,        lds + (BB) + widB); \
    gld_lds16(aSt + (size_t)(KT) * KTB + 2048, lds + (BB) + 8192 + widB); }

__global__ __launch_bounds__(512, 2)
void gemm_dist(const char* __restrict__ Qt, const int* __restrict__ sqi,
               unsigned short* __restrict__ Db) {
    __shared__ char lds[131072];   // 128 KB = 4 bufs x (A0,A1,B0,B1 of 8KB)
    const int tid = threadIdx.x;
    const int wid = tid >> 6, lane = tid & 63;
    const int wr = wid >> 2, wc = wid & 3;
    const int fr = lane & 15, ksub = lane >> 4;
    const int widB = wid * 1024;

    int rA[4], rB[4];
#pragma unroll
    for (int m = 0; m < 4; ++m) rA[m] = (ksub * 128 + m * 16 + fr) * 16;
#pragma unroll
    for (int n = 0; n < 4; ++n) rB[n] = (ksub * 128 + (wc & 1) * 64 + n * 16 + fr) * 16;
    const int aRegOff = wr * 8192;
    const int bRegOff = 16384 + (wc >> 1) * 8192;

    const int swz = (blockIdx.x & 7) * 32 + (blockIdx.x >> 3);  // XCD-chunked
    const int bi = swz >> 4, bj = swz & 15;
    const int rowC0 = bi * 256, colC0 = bj * 256;

    const int srow = tid & 127;
    const int sks = tid >> 7;
    const char* aSt = Qt + ((size_t)sks * 4096 + rowC0 + srow) * 16;
    const char* bSt = Qt + ((size_t)sks * 4096 + colC0 + srow) * 16;

    intx4 acc[2][4][4];
#pragma unroll
    for (int a0 = 0; a0 < 2; ++a0)
#pragma unroll
    for (int a1 = 0; a1 < 4; ++a1)
#pragma unroll
    for (int a2 = 0; a2 < 4; ++a2) acc[a0][a1][a2] = (intx4){0, 0, 0, 0};
    intx4 aflo[4], afhi[4], bfv[4];

    // prologue: stage t0 -> buf0, t1 -> buf1; vmcnt(4) = t0 landed
    STG_ALL(0, 0);
    STG_ALL(1, 32768);
    VMCNT4();
    BAR();

    int cb = 0, sb = 65536;   // current / staging(t+2) buffer byte base
    for (int t = 0; t < NKT; ++t) {
        const char* bufA = lds + cb + aRegOff;
        const char* bufBp = lds + cb + bRegOff;
#pragma unroll
        for (int m = 0; m < 4; ++m) aflo[m] = *(const intx4*)(bufA + rA[m]);
#pragma unroll
        for (int m = 0; m < 4; ++m) afhi[m] = *(const intx4*)(bufA + 1024 + rA[m]);
#pragma unroll
        for (int n = 0; n < 4; ++n) bfv[n] = *(const intx4*)(bufBp + rB[n]);
        if (t < NKT - 2) { STG_ALL(t + 2, sb); VMCNT4(); }
        else if (t == NKT - 2) { VMCNT0(); }
        BAR();
        PRIO1(); MM8(0, aflo); MM8(1, afhi); PRIO0();
        cb += 32768; if (cb >= 131072) cb = 0;
        sb += 32768; if (sb >= 131072) sb = 0;
    }

    // epilogue: D[i][j] = bf16( (v>0) ? sqrt(v)/24 : 1e-6 ), v exact int32
#pragma unroll
    for (int MH = 0; MH < 2; ++MH)
#pragma unroll
    for (int n = 0; n < 4; ++n) {
        const int col = colC0 + wc * 64 + n * 16 + fr;
        const int sqc = sqi[col];
#pragma unroll
        for (int m = 0; m < 4; ++m) {
            const int row0 = rowC0 + wr * 128 + MH * 64 + m * 16 + ksub * 4;
#pragma unroll
            for (int r = 0; r < 4; ++r) {
                const int v = sqi[row0 + r] + sqc - 2 * acc[MH][n][m][r];
                const float d = (v > 0) ? sqrtf((float)v) * QINV : 1e-6f;
                Db[(size_t)(row0 + r) * N_DIM + col] = f2bf(d);
            }
        }
    }
}

// ---- Kernel 2: row stats + third-class scan + loss + DETERMINISTIC sum -----
// int8 labels (4KB scans vs 16KB); per-block loss accumulated into a ull
// fixed-point accumulator (2^26) via atomicAdd — integer add is exactly
// associative -> deterministic. Completion counter: the 4096th block to
// finish converts and writes out[0] (fences around the atomics).
__global__ __launch_bounds__(256)
void stats_loss(const unsigned short* __restrict__ Db, const char* __restrict__ tgt8,
                ull* __restrict__ accum, unsigned* __restrict__ counter,
                float* __restrict__ out) {
    const int i = blockIdx.x, tid = threadIdx.x;
    const int lane = tid & 63, wave = tid >> 6;
    const int ti = tgt8[i];
    const unsigned short* row = Db + (size_t)i * N_DIM;
    ull kmax = 0ULL, kmin = ~0ULL;
#pragma unroll
    for (int it = 0; it < 2; ++it) {
        const int j0 = (it * 256 + tid) * 8;
        ushort8 d = *(const ushort8*)(row + j0);
        const ull tl8 = *(const ull*)(tgt8 + j0);
#pragma unroll
        for (int e = 0; e < 8; ++e) {
            const int j = j0 + e;
            const int tl = (int)((tl8 >> (8 * e)) & 0xff);
            const ull db = (ull)d[e] << 32;
            if (tl == ti) { ull k = db | (unsigned)j;  if (k > kmax) kmax = k; }
            else          { ull k = db | (unsigned)~j; if (k < kmin) kmin = k; }
        }
    }
#pragma unroll
    for (int off = 32; off; off >>= 1) {
        ull o = __shfl_xor(kmax, off); if (o > kmax) kmax = o;
        o = __shfl_xor(kmin, off);     if (o < kmin) kmin = o;
    }
    __shared__ ull sW[8];
    if (lane == 0) { sW[wave] = kmax; sW[4 + wave] = kmin; }
    __syncthreads();
    ull km = sW[0], kn = sW[4];
#pragma unroll
    for (int w2 = 1; w2 < 4; ++w2) {
        if (sW[w2] > km) km = sW[w2];
        if (sW[4 + w2] < kn) kn = sW[4 + w2];
    }
    const float ap = bf2f((unsigned short)(km >> 32));
    const int p = (int)(unsigned)(km & 0xFFFFFFFFu);
    const float an = bf2f((unsigned short)(kn >> 32));
    const int q = (int)~(unsigned)(kn & 0xFFFFFFFFu);

    // phase 2: third-class min over row q (labels != ti and != tgt[q])
    const int lq = tgt8[q];
    const unsigned short* rowq = Db + (size_t)q * N_DIM;
    ull kr = ~0ULL;
#pragma unroll
    for (int it = 0; it < 2; ++it) {
        const int j0 = (it * 256 + tid) * 8;
        ushort8 d = *(const ushort8*)(rowq + j0);
        const ull tl8 = *(const ull*)(tgt8 + j0);
#pragma unroll
        for (int e = 0; e < 8; ++e) {
            const int j = j0 + e;
            const int tl = (int)((tl8 >> (8 * e)) & 0xff);
            if (tl != ti && tl != lq) {
                ull k = ((ull)d[e] << 32) | (unsigned)~j;
                if (k < kr) kr = k;
            }
        }
    }
#pragma unroll
    for (int off = 32; off; off >>= 1) {
        ull o = __shfl_xor(kr, off); if (o < kr) kr = o;
    }
    __shared__ ull sR[4];
    if (lane == 0) sR[wave] = kr;
    __syncthreads();
    if (tid == 0) {
        ull kk = sR[0];
#pragma unroll
        for (int w2 = 1; w2 < 4; ++w2) if (sR[w2] < kk) kk = sR[w2];
        const float okmin = bf2f((unsigned short)(kk >> 32));
        const int r = (int)~(unsigned)(kk & 0xFFFFFFFFu);
        const float an2 = bf2f(Db[(size_t)p * N_DIM + q]);
        const float an3 = bf2f(Db[(size_t)i * N_DIM + r]);
        const float loss = fmaxf(ap - an, 0.f) + fabsf(an - an2) + fabsf(an3 - okmin);
        atomicAdd(accum, (ull)llroundf(loss * FIXP));
        __threadfence();
        const unsigned c = atomicAdd(counter, 1u);
        if (c == N_DIM - 1) {
            __threadfence();
            const ull s = atomicAdd(accum, 0ULL);   // coherent read-back
            out[0] = (float)((double)s / (double)FIXP / (double)N_DIM);
        }
    }
}

extern "C" void kernel_launch(void* const* d_in, const int* in_sizes, int n_in,
                              void* d_out, int out_size, void* d_ws, size_t ws_size,
                              hipStream_t stream) {
    const float* X = (const float*)d_in[0];
    const int* tgt = (const int*)d_in[1];
    float* out = (float*)d_out;

    char* w = (char*)d_ws;
    char* Qt = w;                                             // 8 MB (k-major)
    unsigned short* Db = (unsigned short*)(w + ((size_t)16 << 20));  // 32 MB bf16
    int* sqi = (int*)(w + ((size_t)80 << 20));                // 16 KB
    char* tgt8 = (char*)(sqi + N_DIM);                        // 4 KB
    ull* accum = (ull*)(tgt8 + 4096);                         // 8 B
    unsigned* counter = (unsigned*)(accum + 1);               // 4 B

    hipMemsetAsync(accum, 0, 16, stream);
    prep_kernel<<<N_DIM, 256, 0, stream>>>(X, tgt, Qt, sqi, tgt8);
    gemm_dist<<<256, 512, 0, stream>>>(Qt, sqi, Db);
    stats_loss<<<N_DIM, 256, 0, stream>>>(Db, tgt8, accum, counter, out);
}

// Round 19
// 76.786 us; speedup vs baseline: 2.4137x; 2.4137x over previous
//
#include <hip/hip_runtime.h>
#include <hip/hip_bf16.h>
#include <cstdint>

#define N_DIM 4096
#define K_DIM 2048           // i8 elements per row
#define NKT 32               // 32 K-tiles of 64
#define QSCALE 24.0f
#define QINV (1.0f / 24.0f)

typedef float floatx4 __attribute__((ext_vector_type(4)));
typedef int intx4 __attribute__((ext_vector_type(4)));
typedef unsigned short ushort8 __attribute__((ext_vector_type(8)));
typedef unsigned long long ull;

__device__ __forceinline__ unsigned short f2bf(float f) {
    unsigned int u = __builtin_bit_cast(unsigned int, f);
    unsigned int r = (u + 0x7fffu + ((u >> 16) & 1u)) >> 16;  // RNE
    return (unsigned short)r;
}

__device__ __forceinline__ float bf2f(unsigned short b) {
    return __uint_as_float(((unsigned)b) << 16);
}

__device__ __forceinline__ void gld_lds16(const void* g, void* l) {
    __builtin_amdgcn_global_load_lds(
        (const __attribute__((address_space(1))) unsigned int*)g,
        (__attribute__((address_space(3))) unsigned int*)l,
        16, 0, 0);
}

// ---- Kernel 0: quantize fp32 -> int8 (scale 24) into k-major panels --------
// Qt layout: byte(kslot, row) = (kslot*4096 + row)*16, kslot = k/16 (0..127).
// Blocks 0..15 also convert tgt (int32, labels 0..63) -> tgt8 (int8).
__global__ __launch_bounds__(256)
void prep_kernel(const float* __restrict__ X, const int* __restrict__ tgt,
                 char* __restrict__ Qt, int* __restrict__ sqi,
                 char* __restrict__ tgt8) {
    const int row = blockIdx.x;
    const int tid = threadIdx.x;
    if (row < 16) tgt8[row * 256 + tid] = (char)tgt[row * 256 + tid];
    const float* xr = X + (size_t)row * K_DIM;
    floatx4 a = *(const floatx4*)(xr + tid * 8);
    floatx4 b = *(const floatx4*)(xr + tid * 8 + 4);
    int s = 0;
    unsigned lo = 0, hi = 0;
#pragma unroll
    for (int e = 0; e < 4; ++e) {
        int v = __float2int_rn(a[e] * QSCALE);
        v = min(127, max(-127, v));
        s += v * v;
        lo |= ((unsigned)(v & 0xff)) << (8 * e);
        int w = __float2int_rn(b[e] * QSCALE);
        w = min(127, max(-127, w));
        s += w * w;
        hi |= ((unsigned)(w & 0xff)) << (8 * e);
    }
    *(int2*)(Qt + ((size_t)(tid >> 1) * 4096 + row) * 16 + (tid & 1) * 8) =
        make_int2((int)lo, (int)hi);
#pragma unroll
    for (int off = 32; off; off >>= 1) s += __shfl_down(s, off);
    __shared__ int wsum[4];
    const int wave = tid >> 6, lane = tid & 63;
    if (lane == 0) wsum[wave] = s;
    __syncthreads();
    if (tid == 0) sqi[row] = wsum[0] + wsum[1] + wsum[2] + wsum[3];
}

// ---- Kernel 1: 256x256 int8 MFMA GEMM + bf16 distance epilogue -------------
// R17 kernel verbatim (best measured: 45.0 us, VGPR 108, 0 bank conflicts,
// FETCH 33 MB, absmax 0.0625). Merged single phase per K-tile, quad-buffered
// 128KB LDS:
//   tile t: [RD 12 b128 | STG all 4 halves of (t+2) | vmcnt(4) | BAR | 32 MFMA]
#define BAR() __builtin_amdgcn_s_barrier()
#define PRIO1() __builtin_amdgcn_s_setprio(1)
#define PRIO0() __builtin_amdgcn_s_setprio(0)
#define VMCNT4() asm volatile("s_waitcnt vmcnt(4)" ::: "memory")
#define VMCNT0() asm volatile("s_waitcnt vmcnt(0)" ::: "memory")
#define MM8(MHI, AF) { _Pragma("unroll") for (int n_ = 0; n_ < 4; ++n_) { \
    _Pragma("unroll") for (int m_ = 0; m_ < 4; ++m_) { \
        acc[MHI][n_][m_] = __builtin_amdgcn_mfma_i32_16x16x64_i8( \
            AF[m_], bfv[n_], acc[MHI][n_][m_], 0, 0, 0); } } }
#define KTB 262144   // one K-tile advance in Qt = 4 kslots * 4096 rows * 16B
#define STG_ALL(KT, BB) { \
    gld_lds16(bSt + (size_t)(KT) * KTB,        lds + (BB) + 16384 + widB); \
    gld_lds16(bSt + (size_t)(KT) * KTB + 2048, lds + (BB) + 24576 + widB); \
    gld_lds16(aSt + (size_t)(KT) * KTB,        lds + (BB) + widB); \
    gld_lds16(aSt + (size_t)(KT) * KTB + 2048, lds + (BB) + 8192 + widB); }

__global__ __launch_bounds__(512, 2)
void gemm_dist(const char* __restrict__ Qt, const int* __restrict__ sqi,
               unsigned short* __restrict__ Db) {
    __shared__ char lds[131072];   // 128 KB = 4 bufs x (A0,A1,B0,B1 of 8KB)
    const int tid = threadIdx.x;
    const int wid = tid >> 6, lane = tid & 63;
    const int wr = wid >> 2, wc = wid & 3;
    const int fr = lane & 15, ksub = lane >> 4;
    const int widB = wid * 1024;

    int rA[4], rB[4];
#pragma unroll
    for (int m = 0; m < 4; ++m) rA[m] = (ksub * 128 + m * 16 + fr) * 16;
#pragma unroll
    for (int n = 0; n < 4; ++n) rB[n] = (ksub * 128 + (wc & 1) * 64 + n * 16 + fr) * 16;
    const int aRegOff = wr * 8192;
    const int bRegOff = 16384 + (wc >> 1) * 8192;

    const int swz = (blockIdx.x & 7) * 32 + (blockIdx.x >> 3);  // XCD-chunked
    const int bi = swz >> 4, bj = swz & 15;
    const int rowC0 = bi * 256, colC0 = bj * 256;

    const int srow = tid & 127;
    const int sks = tid >> 7;
    const char* aSt = Qt + ((size_t)sks * 4096 + rowC0 + srow) * 16;
    const char* bSt = Qt + ((size_t)sks * 4096 + colC0 + srow) * 16;

    intx4 acc[2][4][4];
#pragma unroll
    for (int a0 = 0; a0 < 2; ++a0)
#pragma unroll
    for (int a1 = 0; a1 < 4; ++a1)
#pragma unroll
    for (int a2 = 0; a2 < 4; ++a2) acc[a0][a1][a2] = (intx4){0, 0, 0, 0};
    intx4 aflo[4], afhi[4], bfv[4];

    // prologue: stage t0 -> buf0, t1 -> buf1; vmcnt(4) = t0 landed
    STG_ALL(0, 0);
    STG_ALL(1, 32768);
    VMCNT4();
    BAR();

    int cb = 0, sb = 65536;   // current / staging(t+2) buffer byte base
    for (int t = 0; t < NKT; ++t) {
        const char* bufA = lds + cb + aRegOff;
        const char* bufBp = lds + cb + bRegOff;
#pragma unroll
        for (int m = 0; m < 4; ++m) aflo[m] = *(const intx4*)(bufA + rA[m]);
#pragma unroll
        for (int m = 0; m < 4; ++m) afhi[m] = *(const intx4*)(bufA + 1024 + rA[m]);
#pragma unroll
        for (int n = 0; n < 4; ++n) bfv[n] = *(const intx4*)(bufBp + rB[n]);
        if (t < NKT - 2) { STG_ALL(t + 2, sb); VMCNT4(); }
        else if (t == NKT - 2) { VMCNT0(); }
        BAR();
        PRIO1(); MM8(0, aflo); MM8(1, afhi); PRIO0();
        cb += 32768; if (cb >= 131072) cb = 0;
        sb += 32768; if (sb >= 131072) sb = 0;
    }

    // epilogue: D[i][j] = bf16( (v>0) ? sqrt(v)/24 : 1e-6 ), v exact int32
#pragma unroll
    for (int MH = 0; MH < 2; ++MH)
#pragma unroll
    for (int n = 0; n < 4; ++n) {
        const int col = colC0 + wc * 64 + n * 16 + fr;
        const int sqc = sqi[col];
#pragma unroll
        for (int m = 0; m < 4; ++m) {
            const int row0 = rowC0 + wr * 128 + MH * 64 + m * 16 + ksub * 4;
#pragma unroll
            for (int r = 0; r < 4; ++r) {
                const int v = sqi[row0 + r] + sqc - 2 * acc[MH][n][m][r];
                const float d = (v > 0) ? sqrtf((float)v) * QINV : 1e-6f;
                Db[(size_t)(row0 + r) * N_DIM + col] = f2bf(d);
            }
        }
    }
}

// ---- Kernel 2: fused row stats + third-class scan + loss (bf16 D) ----------
// R16 structure (lossArr out, NO device-scope fences/atomics — the R18
// single-kernel termination cost 4096 L2-writeback fences = 10x regression).
// Labels via int8 tgt8 (4KB scans). Packed-key selections bit-identical.
__global__ __launch_bounds__(256)
void stats_loss(const unsigned short* __restrict__ Db, const char* __restrict__ tgt8,
                float* __restrict__ lossArr) {
    const int i = blockIdx.x, tid = threadIdx.x;
    const int lane = tid & 63, wave = tid >> 6;
    const int ti = tgt8[i];
    const unsigned short* row = Db + (size_t)i * N_DIM;
    ull kmax = 0ULL, kmin = ~0ULL;
#pragma unroll
    for (int it = 0; it < 2; ++it) {
        const int j0 = (it * 256 + tid) * 8;
        ushort8 d = *(const ushort8*)(row + j0);
        const ull tl8 = *(const ull*)(tgt8 + j0);
#pragma unroll
        for (int e = 0; e < 8; ++e) {
            const int j = j0 + e;
            const int tl = (int)((tl8 >> (8 * e)) & 0xff);
            const ull db = (ull)d[e] << 32;
            if (tl == ti) { ull k = db | (unsigned)j;  if (k > kmax) kmax = k; }
            else          { ull k = db | (unsigned)~j; if (k < kmin) kmin = k; }
        }
    }
#pragma unroll
    for (int off = 32; off; off >>= 1) {
        ull o = __shfl_xor(kmax, off); if (o > kmax) kmax = o;
        o = __shfl_xor(kmin, off);     if (o < kmin) kmin = o;
    }
    __shared__ ull sW[8];
    if (lane == 0) { sW[wave] = kmax; sW[4 + wave] = kmin; }
    __syncthreads();
    ull km = sW[0], kn = sW[4];
#pragma unroll
    for (int w2 = 1; w2 < 4; ++w2) {
        if (sW[w2] > km) km = sW[w2];
        if (sW[4 + w2] < kn) kn = sW[4 + w2];
    }
    const float ap = bf2f((unsigned short)(km >> 32));
    const int p = (int)(unsigned)(km & 0xFFFFFFFFu);
    const float an = bf2f((unsigned short)(kn >> 32));
    const int q = (int)~(unsigned)(kn & 0xFFFFFFFFu);

    // phase 2: third-class min over row q (labels != ti and != tgt[q])
    const int lq = tgt8[q];
    const unsigned short* rowq = Db + (size_t)q * N_DIM;
    ull kr = ~0ULL;
#pragma unroll
    for (int it = 0; it < 2; ++it) {
        const int j0 = (it * 256 + tid) * 8;
        ushort8 d = *(const ushort8*)(rowq + j0);
        const ull tl8 = *(const ull*)(tgt8 + j0);
#pragma unroll
        for (int e = 0; e < 8; ++e) {
            const int j = j0 + e;
            const int tl = (int)((tl8 >> (8 * e)) & 0xff);
            if (tl != ti && tl != lq) {
                ull k = ((ull)d[e] << 32) | (unsigned)~j;
                if (k < kr) kr = k;
            }
        }
    }
#pragma unroll
    for (int off = 32; off; off >>= 1) {
        ull o = __shfl_xor(kr, off); if (o < kr) kr = o;
    }
    __shared__ ull sR[4];
    if (lane == 0) sR[wave] = kr;
    __syncthreads();
    if (tid == 0) {
        ull kk = sR[0];
#pragma unroll
        for (int w2 = 1; w2 < 4; ++w2) if (sR[w2] < kk) kk = sR[w2];
        const float okmin = bf2f((unsigned short)(kk >> 32));
        const int r = (int)~(unsigned)(kk & 0xFFFFFFFFu);
        const float an2 = bf2f(Db[(size_t)p * N_DIM + q]);
        const float an3 = bf2f(Db[(size_t)i * N_DIM + r]);
        lossArr[i] = fmaxf(ap - an, 0.f) + fabsf(an - an2) + fabsf(an3 - okmin);
    }
}

// ---- Kernel 3: final sum / n ------------------------------------------------
__global__ __launch_bounds__(256)
void finred(const float* __restrict__ lossArr, float* __restrict__ out) {
    const int tid = threadIdx.x;
    float s = 0.f;
    for (int j = tid; j < N_DIM; j += 256) s += lossArr[j];
#pragma unroll
    for (int off = 32; off; off >>= 1) s += __shfl_down(s, off);
    __shared__ float w[4];
    const int wave = tid >> 6, lane = tid & 63;
    if (lane == 0) w[wave] = s;
    __syncthreads();
    if (tid == 0) out[0] = (w[0] + w[1] + w[2] + w[3]) * (1.0f / (float)N_DIM);
}

extern "C" void kernel_launch(void* const* d_in, const int* in_sizes, int n_in,
                              void* d_out, int out_size, void* d_ws, size_t ws_size,
                              hipStream_t stream) {
    const float* X = (const float*)d_in[0];
    const int* tgt = (const int*)d_in[1];
    float* out = (float*)d_out;

    char* w = (char*)d_ws;
    char* Qt = w;                                             // 8 MB (k-major)
    unsigned short* Db = (unsigned short*)(w + ((size_t)16 << 20));  // 32 MB bf16
    int* sqi = (int*)(w + ((size_t)80 << 20));                // 16 KB
    char* tgt8 = (char*)(sqi + N_DIM);                        // 4 KB
    float* lossArr = (float*)(tgt8 + 4096);                   // 16 KB

    prep_kernel<<<N_DIM, 256, 0, stream>>>(X, tgt, Qt, sqi, tgt8);
    gemm_dist<<<256, 512, 0, stream>>>(Qt, sqi, Db);
    stats_loss<<<N_DIM, 256, 0, stream>>>(Db, tgt8, lossArr);
    finred<<<1, 256, 0, stream>>>(lossArr, out);
}